// Round 1
// baseline (71.921 us; speedup 1.0000x reference)
//
#include <hip/hip_runtime.h>
#include <math.h>

#define HIDDEN 1000
#define K4 250   // HIDDEN / 4 float4s per row

// Wave-level dot product of two 1000-float vectors (both 16B aligned).
// Returns full sum in ALL lanes (butterfly reduce).
__device__ __forceinline__ float wave_dot1000(const float* __restrict__ w,
                                              const float* __restrict__ v,
                                              int lane) {
  const float4* w4 = reinterpret_cast<const float4*>(w);
  const float4* v4 = reinterpret_cast<const float4*>(v);
  float acc = 0.f;
  for (int c = lane; c < K4; c += 64) {
    float4 a = w4[c];
    float4 b = v4[c];
    acc = fmaf(a.x, b.x, acc);
    acc = fmaf(a.y, b.y, acc);
    acc = fmaf(a.z, b.z, acc);
    acc = fmaf(a.w, b.w, acc);
  }
  #pragma unroll
  for (int off = 32; off; off >>= 1) acc += __shfl_xor(acc, off);
  return acc;
}

__device__ __forceinline__ float sigmoidf_(float x) {
  return 1.f / (1.f + expf(-x));
}

// Phase A: all W_hh matvecs (parallel across layers) + fused layer-0 cell.
// Blocks [0,250): layer-0 neurons (wave per neuron j: 3 gh dots + tiny gi + gate).
// Blocks [250,5500): gh rows for layers 1..7 (wave per row), written to gh_ws.
__global__ void gru_phaseA(const float* __restrict__ x,        // [2]
                           const float* __restrict__ hiddens,  // [8*1000]
                           const float* __restrict__ Wih0,     // [3000*2]
                           const float* __restrict__ Whh,      // [8*3000*1000]
                           const float* __restrict__ bih,      // [8*3000]
                           const float* __restrict__ bhh,      // [8*3000]
                           float* __restrict__ gh_ws,          // [7*3000]
                           float* __restrict__ h_buf,          // [8*1000]
                           float* __restrict__ out)            // [8001]
{
  const int wave = threadIdx.x >> 6;
  const int lane = threadIdx.x & 63;
  const int b = blockIdx.x;

  if (b < 250) {
    const int j = b * 4 + wave;            // neuron 0..999
    const float* h0 = hiddens;             // layer 0 prev hidden
    float ghr = wave_dot1000(Whh + (size_t)(j)         * HIDDEN, h0, lane) + bhh[j];
    float ghz = wave_dot1000(Whh + (size_t)(1000 + j)  * HIDDEN, h0, lane) + bhh[1000 + j];
    float ghn = wave_dot1000(Whh + (size_t)(2000 + j)  * HIDDEN, h0, lane) + bhh[2000 + j];
    if (lane == 0) {
      const float x0 = x[0], x1 = x[1];
      float gir = Wih0[2*j]          * x0 + Wih0[2*j+1]          * x1 + bih[j];
      float giz = Wih0[2*(1000+j)]   * x0 + Wih0[2*(1000+j)+1]   * x1 + bih[1000 + j];
      float gin = Wih0[2*(2000+j)]   * x0 + Wih0[2*(2000+j)+1]   * x1 + bih[2000 + j];
      float r = sigmoidf_(gir + ghr);
      float z = sigmoidf_(giz + ghz);
      float n = tanhf(gin + r * ghn);
      float h = (1.f - z) * n + z * h0[j];
      h_buf[j] = h;
      out[1 + j] = h;
    }
  } else {
    const int rg = (b - 250) * 4 + wave;   // 0..20999
    const int l = rg / 3000 + 1;           // layer 1..7
    const int r = rg % 3000;               // row within layer
    const float* hl = hiddens + (size_t)l * HIDDEN;
    float gh = wave_dot1000(Whh + ((size_t)l * 3000 + r) * HIDDEN, hl, lane)
             + bhh[l * 3000 + r];
    if (lane == 0) gh_ws[rg] = gh;
  }
}

// One layer (l in 1..7): gi matvec + gate, wave per neuron.
__global__ void gru_layer(const int l,
                          const float* __restrict__ hiddens,  // [8*1000]
                          const float* __restrict__ Wih,      // [7*3000*1000]
                          const float* __restrict__ bih,      // [8*3000]
                          const float* __restrict__ gh_ws,    // [7*3000]
                          float* __restrict__ h_buf,          // [8*1000]
                          float* __restrict__ out)            // [8001]
{
  const int wave = threadIdx.x >> 6;
  const int lane = threadIdx.x & 63;
  const int j = blockIdx.x * 4 + wave;     // neuron 0..999
  const float* hin = h_buf + (size_t)(l - 1) * HIDDEN;
  const float* W = Wih + (size_t)(l - 1) * 3000 * HIDDEN;

  float gir = wave_dot1000(W + (size_t)(j)        * HIDDEN, hin, lane) + bih[l*3000 + j];
  float giz = wave_dot1000(W + (size_t)(1000 + j) * HIDDEN, hin, lane) + bih[l*3000 + 1000 + j];
  float gin = wave_dot1000(W + (size_t)(2000 + j) * HIDDEN, hin, lane) + bih[l*3000 + 2000 + j];

  if (lane == 0) {
    float ghr = gh_ws[(l-1)*3000 + j];
    float ghz = gh_ws[(l-1)*3000 + 1000 + j];
    float ghn = gh_ws[(l-1)*3000 + 2000 + j];
    float hp  = hiddens[(size_t)l * HIDDEN + j];
    float r = sigmoidf_(gir + ghr);
    float z = sigmoidf_(giz + ghz);
    float n = tanhf(gin + r * ghn);
    float h = (1.f - z) * n + z * hp;
    h_buf[l * HIDDEN + j] = h;
    out[1 + l * HIDDEN + j] = h;
  }
}

// flow = W_out @ h7 + b_out
__global__ void gru_flow(const float* __restrict__ Wout,   // [1000]
                         const float* __restrict__ bout,   // [1]
                         const float* __restrict__ h_buf,  // [8*1000]
                         float* __restrict__ out)          // [8001]
{
  const int t = threadIdx.x;               // 256 threads
  const float* h7 = h_buf + 7 * HIDDEN;
  float acc = 0.f;
  for (int i = t; i < HIDDEN; i += 256) acc += Wout[i] * h7[i];
  #pragma unroll
  for (int off = 32; off; off >>= 1) acc += __shfl_xor(acc, off);
  __shared__ float s[4];
  const int wave = t >> 6, lane = t & 63;
  if (lane == 0) s[wave] = acc;
  __syncthreads();
  if (t == 0) out[0] = s[0] + s[1] + s[2] + s[3] + bout[0];
}

extern "C" void kernel_launch(void* const* d_in, const int* in_sizes, int n_in,
                              void* d_out, int out_size, void* d_ws, size_t ws_size,
                              hipStream_t stream) {
  const float* x       = (const float*)d_in[0];
  const float* hiddens = (const float*)d_in[1];
  const float* Wih0    = (const float*)d_in[2];
  const float* Wih     = (const float*)d_in[3];
  const float* Whh     = (const float*)d_in[4];
  const float* bih     = (const float*)d_in[5];
  const float* bhh     = (const float*)d_in[6];
  const float* Wout    = (const float*)d_in[7];
  const float* bout    = (const float*)d_in[8];
  float* out   = (float*)d_out;
  float* gh_ws = (float*)d_ws;          // 21000 floats (layers 1..7 gh)
  float* h_buf = gh_ws + 21000;         // 8000 floats (per-layer h, 16B-aligned)

  gru_phaseA<<<5500, 256, 0, stream>>>(x, hiddens, Wih0, Whh, bih, bhh,
                                       gh_ws, h_buf, out);
  for (int l = 1; l < 8; ++l) {
    gru_layer<<<250, 256, 0, stream>>>(l, hiddens, Wih, bih, gh_ws, h_buf, out);
  }
  gru_flow<<<1, 256, 0, stream>>>(Wout, bout, h_buf, out);
}